// Round 2
// baseline (146.559 us; speedup 1.0000x reference)
//
#include <hip/hip_runtime.h>

// Problem constants
#define Bc  32
#define Nc  16
#define Tc  64
#define Hc  256
#define NTc 1024   // N*T

// Workspace layout (float offsets):
//   M    [B*T*H]  = 524288  (mean over neighbors, includes the /16)
//   Wsum [B*T]    = 2048    (column sums of P over all q, atomic)
#define M_OFF  0
#define W_OFF  (Bc * Tc * Hc)

// ---------------------------------------------------------------------------
// Kernel 1: M[b,t,h] = (1/16) * sum_i neigh[b,i,t,h]
// 512 blocks x 256 threads; one float4 per thread; coalesced in h.
// ---------------------------------------------------------------------------
__global__ __launch_bounds__(256) void mean_kernel(const float* __restrict__ neigh,
                                                   float* __restrict__ M) {
    int idx = blockIdx.x * 256 + threadIdx.x;   // over B*T*(H/4) = 131072
    int h4 = idx & 63;                          // float4 index within H
    int bt = idx >> 6;                          // b*T + t
    int b  = bt >> 6;
    int t  = bt & 63;
    const float4* p = (const float4*)neigh
                    + ((size_t)b * Nc * Tc * Hc + (size_t)t * Hc) / 4 + h4;
    float4 s = make_float4(0.f, 0.f, 0.f, 0.f);
#pragma unroll
    for (int i = 0; i < Nc; i++) {
        float4 v = p[(size_t)i * (Tc * Hc / 4)];
        s.x += v.x; s.y += v.y; s.z += v.z; s.w += v.w;
    }
    const float r = 1.0f / 16.0f;
    s.x *= r; s.y *= r; s.z *= r; s.w *= r;
    ((float4*)M)[idx] = s;
}

// ---------------------------------------------------------------------------
// Kernel 2 (fused): block = (b, i).  X = neigh[b,i] (64t' x 256h).
//   S[t'][t] = X @ node[b]^T / sqrt(nb);  P = softmax_t(S)  (kept in LDS);
//   Wsum[b,t] += column sums of P (atomic);
//   out[b, i*64+t', :] = P @ M[b]   (h-chunked, 64 at a time).
// 256 threads, 4x4 register tile per thread (tx -> cols, ty -> rows).
// ---------------------------------------------------------------------------
__global__ __launch_bounds__(256) void fused_kernel(const float* __restrict__ neigh,
                                                    const float* __restrict__ node,
                                                    const int*   __restrict__ nbr,
                                                    const float* __restrict__ M,
                                                    float* __restrict__ out,
                                                    float* __restrict__ Wsum) {
    __shared__ float Xs[64][68];   // [t'][k-chunk]
    __shared__ float Ns[64][68];   // [k-chunk][t]  (transposed node)
    __shared__ float Ps[64][68];   // [t'][t]       (softmax result)
    __shared__ float Ms[64][68];   // [t][h-chunk]

    int b  = blockIdx.x >> 4;
    int i  = blockIdx.x & 15;
    int q0 = i << 6;
    int tx = threadIdx.x & 15;
    int ty = threadIdx.x >> 4;

    // neighbors_number: reference dtype int64; harness may upload int32.
    // Values are in [1,16] so nbr[1]==0 <=> int64 (high word of elem 0).
    int nb = (nbr[1] == 0) ? nbr[2 * b] : nbr[b];
    float rscale = rsqrtf((float)nb);

    const float* Xg = neigh + (size_t)b * (Nc * Tc * Hc) + (size_t)q0 * Hc;
    const float* Ng = node  + (size_t)b * (Tc * Hc);
    const float* Mb = M     + (size_t)b * (Tc * Hc);

    float acc[4][4];
#pragma unroll
    for (int r = 0; r < 4; r++)
#pragma unroll
        for (int j = 0; j < 4; j++) acc[r][j] = 0.f;

    // ---- Phase A: S = X @ node^T over K=256 in chunks of 64 ----
    for (int k0 = 0; k0 < Hc; k0 += 64) {
#pragma unroll
        for (int r = 0; r < 4; r++) {
            int row = r * 16 + ty;
            float4 xv = *(const float4*)(Xg + (size_t)row * Hc + k0 + tx * 4);
            *(float4*)&Xs[row][tx * 4] = xv;
            float4 nv = *(const float4*)(Ng + (size_t)row * Hc + k0 + tx * 4);
            Ns[tx * 4 + 0][row] = nv.x;
            Ns[tx * 4 + 1][row] = nv.y;
            Ns[tx * 4 + 2][row] = nv.z;
            Ns[tx * 4 + 3][row] = nv.w;
        }
        __syncthreads();

#pragma unroll
        for (int kk = 0; kk < 64; kk += 4) {
            float xq[4][4];
#pragma unroll
            for (int r = 0; r < 4; r++)
                *(float4*)&xq[r][0] = *(const float4*)&Xs[ty * 4 + r][kk];
#pragma unroll
            for (int s = 0; s < 4; s++) {
                float4 nv = *(const float4*)&Ns[kk + s][tx * 4];
#pragma unroll
                for (int r = 0; r < 4; r++) {
                    acc[r][0] += xq[r][s] * nv.x;
                    acc[r][1] += xq[r][s] * nv.y;
                    acc[r][2] += xq[r][s] * nv.z;
                    acc[r][3] += xq[r][s] * nv.w;
                }
            }
        }
        __syncthreads();
    }

    // ---- Softmax over t (row t' is spread over 16 tx-lanes x 4 regs) ----
    float colsum[4] = {0.f, 0.f, 0.f, 0.f};
#pragma unroll
    for (int r = 0; r < 4; r++) {
#pragma unroll
        for (int j = 0; j < 4; j++) acc[r][j] *= rscale;
        float m = fmaxf(fmaxf(acc[r][0], acc[r][1]), fmaxf(acc[r][2], acc[r][3]));
#pragma unroll
        for (int d = 1; d < 16; d <<= 1) m = fmaxf(m, __shfl_xor(m, d));
        float e0 = __expf(acc[r][0] - m);
        float e1 = __expf(acc[r][1] - m);
        float e2 = __expf(acc[r][2] - m);
        float e3 = __expf(acc[r][3] - m);
        float s = e0 + e1 + e2 + e3;
#pragma unroll
        for (int d = 1; d < 16; d <<= 1) s += __shfl_xor(s, d);
        float inv = 1.0f / s;
        float4 pv = make_float4(e0 * inv, e1 * inv, e2 * inv, e3 * inv);
        colsum[0] += pv.x; colsum[1] += pv.y; colsum[2] += pv.z; colsum[3] += pv.w;
        *(float4*)&Ps[ty * 4 + r][tx * 4] = pv;
    }

    // Column sums: reduce over the 4 ty values within each wave (tid bits 4,5),
    // then one atomicAdd per (wave, t).
#pragma unroll
    for (int j = 0; j < 4; j++) {
        colsum[j] += __shfl_xor(colsum[j], 16);
        colsum[j] += __shfl_xor(colsum[j], 32);
    }
    if ((ty & 3) == 0) {
#pragma unroll
        for (int j = 0; j < 4; j++)
            atomicAdd(&Wsum[b * Tc + tx * 4 + j], colsum[j]);
    }
    __syncthreads();   // Ps fully written before Phase B reads it

    // ---- Phase B: out_tile = Ps(64x64) @ M[b](64t x 256h), h-chunked ----
    for (int h0 = 0; h0 < Hc; h0 += 64) {
#pragma unroll
        for (int r = 0; r < 4; r++) {
            int row = r * 16 + ty;
            *(float4*)&Ms[row][tx * 4] =
                *(const float4*)(Mb + (size_t)row * Hc + h0 + tx * 4);
        }
        __syncthreads();

        float oc[4][4];
#pragma unroll
        for (int r = 0; r < 4; r++)
#pragma unroll
            for (int j = 0; j < 4; j++) oc[r][j] = 0.f;

#pragma unroll
        for (int t0 = 0; t0 < 64; t0 += 4) {
            float pq[4][4];
#pragma unroll
            for (int r = 0; r < 4; r++)
                *(float4*)&pq[r][0] = *(const float4*)&Ps[ty * 4 + r][t0];
#pragma unroll
            for (int s = 0; s < 4; s++) {
                float4 mv = *(const float4*)&Ms[t0 + s][tx * 4];
#pragma unroll
                for (int r = 0; r < 4; r++) {
                    oc[r][0] += pq[r][s] * mv.x;
                    oc[r][1] += pq[r][s] * mv.y;
                    oc[r][2] += pq[r][s] * mv.z;
                    oc[r][3] += pq[r][s] * mv.w;
                }
            }
        }

#pragma unroll
        for (int r = 0; r < 4; r++) {
            float4 v = make_float4(oc[r][0], oc[r][1], oc[r][2], oc[r][3]);
            *(float4*)(out + ((size_t)b * NTc + q0 + ty * 4 + r) * Hc + h0 + tx * 4) = v;
        }
        __syncthreads();   // before overwriting Ms next h-chunk
    }
}

// ---------------------------------------------------------------------------
// Kernel 3: W[b,i,t] = Wsum[b,t] / 16  (independent of i)
// ---------------------------------------------------------------------------
__global__ __launch_bounds__(256) void wexp_kernel(const float* __restrict__ Wsum,
                                                   float* __restrict__ Wout) {
    int idx = blockIdx.x * 256 + threadIdx.x;   // over B*N*T = 32768
    int b = idx >> 10;
    int t = idx & 63;
    Wout[idx] = Wsum[b * Tc + t] * (1.0f / 16.0f);
}

// ---------------------------------------------------------------------------
extern "C" void kernel_launch(void* const* d_in, const int* in_sizes, int n_in,
                              void* d_out, int out_size, void* d_ws, size_t ws_size,
                              hipStream_t stream) {
    const float* node  = (const float*)d_in[0];   // (B,T,H)
    const float* neigh = (const float*)d_in[1];   // (B,N,T,H)
    const int*   nbr   = (const int*)d_in[2];     // (B,) int32/int64 (detected)

    float* out = (float*)d_out;                   // (B,NT,H) then W (B,N,T)
    float* ws  = (float*)d_ws;
    float* Mw  = ws + M_OFF;
    float* Ww  = ws + W_OFF;

    hipMemsetAsync(Ww, 0, Bc * Tc * sizeof(float), stream);

    mean_kernel <<<512, 256, 0, stream>>>(neigh, Mw);
    fused_kernel<<<512, 256, 0, stream>>>(neigh, node, nbr, Mw, out, Ww);
    wexp_kernel <<<128, 256, 0, stream>>>(Ww, out + (size_t)Bc * NTc * Hc);
}

// Round 3
// 128.078 us; speedup vs baseline: 1.1443x; 1.1443x over previous
//
#include <hip/hip_runtime.h>

// Problem constants
#define Bc  32
#define Nc  16
#define Tc  64
#define Hc  256
#define NTc 1024   // N*T

// Workspace layout (float offsets):
//   nodeT [B*H*T] = 524288   (node transposed to [b][h][t])
//   M     [B*T*H] = 524288   (mean over neighbors, includes the /16)
//   Wsum  [B*T]   = 2048     (column sums of P over all q, atomic)
#define NT_OFF 0
#define M_OFF  (Bc * Hc * Tc)
#define W_OFF  (M_OFF + Bc * Tc * Hc)

// ---------------------------------------------------------------------------
// Prep kernel, 640 blocks:
//   blocks [0,512):   M[b,t,h] = (1/16) * sum_i neigh[b,i,t,h]
//   blocks [512,640): nodeT[b,h,t] = node[b,t,h]  (one 64x64 tile each)
//                     + zero Wsum
// ---------------------------------------------------------------------------
__global__ __launch_bounds__(256) void prep_kernel(const float* __restrict__ neigh,
                                                   const float* __restrict__ node,
                                                   float* __restrict__ M,
                                                   float* __restrict__ nodeT,
                                                   float* __restrict__ Wsum) {
    __shared__ float Ls[64][68];
    int bk  = blockIdx.x;
    int tid = threadIdx.x;

    if (bk < 512) {
        int idx = bk * 256 + tid;               // over B*T*(H/4) = 131072
        int h4 = idx & 63;
        int bt = idx >> 6;
        int b  = bt >> 6;
        int t  = bt & 63;
        const float4* p = (const float4*)neigh
                        + ((size_t)b * Nc * Tc * Hc + (size_t)t * Hc) / 4 + h4;
        float4 s = make_float4(0.f, 0.f, 0.f, 0.f);
#pragma unroll
        for (int i = 0; i < Nc; i++) {
            float4 v = p[(size_t)i * (Tc * Hc / 4)];
            s.x += v.x; s.y += v.y; s.z += v.z; s.w += v.w;
        }
        const float r = 1.0f / 16.0f;
        s.x *= r; s.y *= r; s.z *= r; s.w *= r;
        ((float4*)M)[idx] = s;
    } else {
        int r  = bk - 512;                      // 0..127
        int b  = r >> 2;
        int hc = r & 3;
        const float* Nb = node + (size_t)b * (Tc * Hc) + hc * 64;
#pragma unroll
        for (int s = 0; s < 4; s++) {
            int e = tid + s * 256;              // 0..1023
            int t  = e >> 4;
            int c4 = e & 15;
            *(float4*)&Ls[t][c4 * 4] = *(const float4*)(Nb + (size_t)t * Hc + c4 * 4);
        }
        if (tid < 16) Wsum[b * Tc + hc * 16 + tid] = 0.f;
        __syncthreads();
        float* NTb = nodeT + (size_t)b * (Hc * Tc) + hc * 64 * Tc;
#pragma unroll
        for (int s = 0; s < 4; s++) {
            int e = tid + s * 256;
            int hr  = e >> 4;
            int tc4 = e & 15;
            float4 v = make_float4(Ls[tc4 * 4 + 0][hr], Ls[tc4 * 4 + 1][hr],
                                   Ls[tc4 * 4 + 2][hr], Ls[tc4 * 4 + 3][hr]);
            *(float4*)(NTb + (size_t)hr * Tc + tc4 * 4) = v;
        }
    }
}

// ---------------------------------------------------------------------------
// Fused kernel: block = (b, i, q-half).  X = neigh[b, i, q0..q0+31] (32 x 256).
//   S[32t'][64t] = X @ node^T / sqrt(nb);  P = softmax_t(S)  (LDS);
//   Wsum[b,t] += column sums of P;
//   out[b, q0+t', :] = P @ M[b]  (h-chunked, 64 at a time, Ms aliases Xs/Ns).
// 1024 blocks x 256 threads; 2x4 register tile; 35 KB LDS -> 4 blocks/CU.
// ---------------------------------------------------------------------------
__global__ __launch_bounds__(256, 4) void fused_kernel(const float* __restrict__ neigh,
                                                       const float* __restrict__ nodeT,
                                                       const int*   __restrict__ nbr,
                                                       const float* __restrict__ M,
                                                       float* __restrict__ out,
                                                       float* __restrict__ Wsum) {
    __shared__ __align__(16) float smem[8960];        // 35840 B
    float (*Xs)[68] = (float(*)[68])smem;             // [32][68]
    float (*Ns)[68] = (float(*)[68])(smem + 2176);    // [64][68]
    float (*Ms)[68] = (float(*)[68])smem;             // [64][68], aliases Xs+Ns
    float (*Ps)[68] = (float(*)[68])(smem + 6528);    // [32][68]
    float* Wtmp     = smem + 8704;                    // [4*64]

    int bk = blockIdx.x;
    int b  = bk >> 5;
    int rem = bk & 31;
    int i  = rem >> 1;
    int q0 = i * 64 + (rem & 1) * 32;

    int tid = threadIdx.x;
    int tx  = tid & 15;
    int ty  = tid >> 4;

    // neighbors_number: reference dtype int64; harness may upload int32.
    // Values in [1,16] so nbr[1]==0 <=> int64 (high word of elem 0).
    int nb = (nbr[1] == 0) ? nbr[2 * b] : nbr[b];
    float rscale = rsqrtf((float)nb);

    const float* Xg  = neigh + (size_t)b * (Nc * Tc * Hc) + (size_t)q0 * Hc;
    const float* NTb = nodeT + (size_t)b * (Hc * Tc);
    const float* Mb  = M     + (size_t)b * (Tc * Hc);

    float acc[2][4];
#pragma unroll
    for (int r = 0; r < 2; r++)
#pragma unroll
        for (int j = 0; j < 4; j++) acc[r][j] = 0.f;

    // ---- Phase A: S = X @ node^T over K=256 in chunks of 64 ----
    for (int k0 = 0; k0 < Hc; k0 += 64) {
#pragma unroll
        for (int s = 0; s < 2; s++) {         // Xs: 32 rows x 16 float4
            int e = tid + s * 256;
            int row = e >> 4, c4 = e & 15;
            *(float4*)&Xs[row][c4 * 4] =
                *(const float4*)(Xg + (size_t)row * Hc + k0 + c4 * 4);
        }
#pragma unroll
        for (int s = 0; s < 4; s++) {         // Ns: 64 rows(k) x 16 float4(t)
            int e = tid + s * 256;
            int kr = e >> 4, c4 = e & 15;
            *(float4*)&Ns[kr][c4 * 4] =
                *(const float4*)(NTb + (size_t)(k0 + kr) * Tc + c4 * 4);
        }
        __syncthreads();

#pragma unroll
        for (int kk = 0; kk < 64; kk += 4) {
            float xq[2][4];
#pragma unroll
            for (int r = 0; r < 2; r++)
                *(float4*)&xq[r][0] = *(const float4*)&Xs[ty * 2 + r][kk];
#pragma unroll
            for (int s = 0; s < 4; s++) {
                float4 nv = *(const float4*)&Ns[kk + s][tx * 4];
#pragma unroll
                for (int r = 0; r < 2; r++) {
                    acc[r][0] += xq[r][s] * nv.x;
                    acc[r][1] += xq[r][s] * nv.y;
                    acc[r][2] += xq[r][s] * nv.z;
                    acc[r][3] += xq[r][s] * nv.w;
                }
            }
        }
        __syncthreads();
    }

    // ---- Softmax over t (row spread over 16 tx-lanes x 4 regs) ----
    float colsum[4] = {0.f, 0.f, 0.f, 0.f};
#pragma unroll
    for (int r = 0; r < 2; r++) {
#pragma unroll
        for (int j = 0; j < 4; j++) acc[r][j] *= rscale;
        float m = fmaxf(fmaxf(acc[r][0], acc[r][1]), fmaxf(acc[r][2], acc[r][3]));
#pragma unroll
        for (int d = 1; d < 16; d <<= 1) m = fmaxf(m, __shfl_xor(m, d));
        float e0 = __expf(acc[r][0] - m);
        float e1 = __expf(acc[r][1] - m);
        float e2 = __expf(acc[r][2] - m);
        float e3 = __expf(acc[r][3] - m);
        float s = e0 + e1 + e2 + e3;
#pragma unroll
        for (int d = 1; d < 16; d <<= 1) s += __shfl_xor(s, d);
        float inv = 1.0f / s;
        float4 pv = make_float4(e0 * inv, e1 * inv, e2 * inv, e3 * inv);
        colsum[0] += pv.x; colsum[1] += pv.y; colsum[2] += pv.z; colsum[3] += pv.w;
        *(float4*)&Ps[ty * 2 + r][tx * 4] = pv;
    }

    // Per-wave column sums (reduce over ty bits inside wave), park in Wtmp.
#pragma unroll
    for (int j = 0; j < 4; j++) {
        colsum[j] += __shfl_xor(colsum[j], 16);
        colsum[j] += __shfl_xor(colsum[j], 32);
    }
    int w = tid >> 6;
    if ((tid & 48) == 0)
        *(float4*)&Wtmp[w * 64 + tx * 4] = make_float4(colsum[0], colsum[1], colsum[2], colsum[3]);

    __syncthreads();   // Ps + Wtmp complete; Phase A reads done (Ms may overwrite)

    if (tid < 64) {
        float s = Wtmp[tid] + Wtmp[64 + tid] + Wtmp[128 + tid] + Wtmp[192 + tid];
        atomicAdd(&Wsum[b * Tc + tid], s);
    }

    // ---- Phase B: out_tile(32 x 256) = Ps @ M[b], h-chunked by 64 ----
    for (int h0 = 0; h0 < Hc; h0 += 64) {
#pragma unroll
        for (int s = 0; s < 4; s++) {         // Ms: 64 rows(t) x 16 float4(h)
            int e = tid + s * 256;
            int tr = e >> 4, c4 = e & 15;
            *(float4*)&Ms[tr][c4 * 4] =
                *(const float4*)(Mb + (size_t)tr * Hc + h0 + c4 * 4);
        }
        __syncthreads();

        float oc[2][4];
#pragma unroll
        for (int r = 0; r < 2; r++)
#pragma unroll
            for (int j = 0; j < 4; j++) oc[r][j] = 0.f;

#pragma unroll
        for (int t0 = 0; t0 < 64; t0 += 4) {
            float pq[2][4];
#pragma unroll
            for (int r = 0; r < 2; r++)
                *(float4*)&pq[r][0] = *(const float4*)&Ps[ty * 2 + r][t0];
#pragma unroll
            for (int s = 0; s < 4; s++) {
                float4 mv = *(const float4*)&Ms[t0 + s][tx * 4];
#pragma unroll
                for (int r = 0; r < 2; r++) {
                    oc[r][0] += pq[r][s] * mv.x;
                    oc[r][1] += pq[r][s] * mv.y;
                    oc[r][2] += pq[r][s] * mv.z;
                    oc[r][3] += pq[r][s] * mv.w;
                }
            }
        }

#pragma unroll
        for (int r = 0; r < 2; r++) {
            float4 v = make_float4(oc[r][0], oc[r][1], oc[r][2], oc[r][3]);
            *(float4*)(out + ((size_t)b * NTc + q0 + ty * 2 + r) * Hc + h0 + tx * 4) = v;
        }
        __syncthreads();   // before overwriting Ms next chunk
    }
}

// ---------------------------------------------------------------------------
// W[b,i,t] = Wsum[b,t] / 16  (independent of i)
// ---------------------------------------------------------------------------
__global__ __launch_bounds__(256) void wexp_kernel(const float* __restrict__ Wsum,
                                                   float* __restrict__ Wout) {
    int idx = blockIdx.x * 256 + threadIdx.x;   // over B*N*T = 32768
    int b = idx >> 10;
    int t = idx & 63;
    Wout[idx] = Wsum[b * Tc + t] * (1.0f / 16.0f);
}

// ---------------------------------------------------------------------------
extern "C" void kernel_launch(void* const* d_in, const int* in_sizes, int n_in,
                              void* d_out, int out_size, void* d_ws, size_t ws_size,
                              hipStream_t stream) {
    const float* node  = (const float*)d_in[0];   // (B,T,H)
    const float* neigh = (const float*)d_in[1];   // (B,N,T,H)
    const int*   nbr   = (const int*)d_in[2];     // (B,) int32/int64 (detected)

    float* out = (float*)d_out;                   // (B,NT,H) then W (B,N,T)
    float* ws  = (float*)d_ws;
    float* NTw = ws + NT_OFF;
    float* Mw  = ws + M_OFF;
    float* Ww  = ws + W_OFF;

    prep_kernel <<<640, 256, 0, stream>>>(neigh, node, Mw, NTw, Ww);
    fused_kernel<<<1024, 256, 0, stream>>>(neigh, NTw, nbr, Mw, out, Ww);
    wexp_kernel <<<128, 256, 0, stream>>>(Ww, out + (size_t)Bc * NTc * Hc);
}

// Round 4
// 106.524 us; speedup vs baseline: 1.3758x; 1.2023x over previous
//
#include <hip/hip_runtime.h>

// Problem constants
#define Bc  32
#define Nc  16
#define Tc  64
#define Hc  256
#define NTc 1024   // N*T

typedef unsigned short u16;
using v8s = __attribute__((ext_vector_type(8))) short;   // 8 bf16 = 4 VGPRs (MFMA A/B frag)
using v4f = __attribute__((ext_vector_type(4))) float;   // MFMA C/D frag

// fp32 -> bf16 round-to-nearest-even (bit manip; inputs finite)
static __device__ __forceinline__ u16 f2bf(float x) {
    unsigned u = __float_as_uint(x);
    unsigned r = u + 0x7fffu + ((u >> 16) & 1u);
    return (u16)(r >> 16);
}
static __device__ __forceinline__ float bf2f(u16 h) {
    return __uint_as_float(((unsigned)h) << 16);
}

// ---------------------------------------------------------------------------
// Prep kernel, 160 blocks:
//  blocks [0,128): MT[b,h,t] = bf16( (1/16) * sum_i neigh[b,i,t,h] )  (transposed mean)
//                  one (b, 64-h chunk) per block; reads neigh once (134 MB total).
//  blocks [128,160): node_hi/node_lo[b,t,h] = bf16 hi/lo split of node; zero Wsum.
// ---------------------------------------------------------------------------
__global__ __launch_bounds__(256) void prep_kernel(const float* __restrict__ neigh,
                                                   const float* __restrict__ node,
                                                   u16* __restrict__ MT,
                                                   u16* __restrict__ NH,
                                                   u16* __restrict__ NL,
                                                   float* __restrict__ Wsum) {
    __shared__ float Ls[64][68];
    int bk = blockIdx.x, tid = threadIdx.x;

    if (bk < 128) {
        int b = bk >> 2, h0 = (bk & 3) << 6;
#pragma unroll
        for (int rep = 0; rep < 4; rep++) {
            int idx = rep * 256 + tid;
            int t = idx >> 4, c4 = idx & 15;
            const float4* p = (const float4*)(neigh + ((size_t)b * Nc * Tc + t) * Hc + h0) + c4;
            float4 a = make_float4(0.f, 0.f, 0.f, 0.f);
#pragma unroll
            for (int i = 0; i < Nc; i++) {
                float4 v = p[(size_t)i * (Tc * Hc / 4)];
                a.x += v.x; a.y += v.y; a.z += v.z; a.w += v.w;
            }
            const float r = 1.0f / 16.0f;
            Ls[t][c4 * 4 + 0] = a.x * r;
            Ls[t][c4 * 4 + 1] = a.y * r;
            Ls[t][c4 * 4 + 2] = a.z * r;
            Ls[t][c4 * 4 + 3] = a.w * r;
        }
        __syncthreads();
        // transpose-write bf16: MT[b][h0+h][t]
#pragma unroll
        for (int rep = 0; rep < 4; rep++) {
            int idx = rep * 256 + tid;
            int h = idx >> 4, t4 = idx & 15;
            ushort4 o;
            o.x = f2bf(Ls[t4 * 4 + 0][h]);
            o.y = f2bf(Ls[t4 * 4 + 1][h]);
            o.z = f2bf(Ls[t4 * 4 + 2][h]);
            o.w = f2bf(Ls[t4 * 4 + 3][h]);
            *(ushort4*)(MT + ((size_t)b * Hc + h0 + h) * Tc + t4 * 4) = o;
        }
    } else {
        int b = bk - 128;
#pragma unroll
        for (int rep = 0; rep < 16; rep++) {
            int idx = rep * 256 + tid;          // over 4096 float4 = 64x256 floats
            int t = idx >> 6, c4 = idx & 63;
            size_t off = ((size_t)b * Tc + t) * Hc + c4 * 4;
            float4 v = *(const float4*)(node + off);
            ushort4 hs, ls;
            hs.x = f2bf(v.x); ls.x = f2bf(v.x - bf2f(hs.x));
            hs.y = f2bf(v.y); ls.y = f2bf(v.y - bf2f(hs.y));
            hs.z = f2bf(v.z); ls.z = f2bf(v.z - bf2f(hs.z));
            hs.w = f2bf(v.w); ls.w = f2bf(v.w - bf2f(hs.w));
            *(ushort4*)(NH + off) = hs;
            *(ushort4*)(NL + off) = ls;
        }
        if (tid < 64) Wsum[b * 64 + tid] = 0.f;
    }
}

// ---------------------------------------------------------------------------
// Fused MFMA kernel: block = (b, i).  X = neigh[b,i] (64q x 256h).
//  Phase A: S(64x64) = X @ node^T / sqrt(nb) via 16x16x32 bf16 MFMA with
//           hi/lo split (3 MFMAs: hh + hl + lh) -> fp32-grade logits.
//  Softmax over t in C-layout registers (wave-local rows), P -> LDS as bf16,
//  column sums -> Wsum (atomic).
//  Phase B: out(64q x 256h) = P @ M, plain bf16 MFMA (K=64), M staged from
//           precomputed MT[h][t].
// 4 waves; wave w owns q-rows w*16..w*16+15 (full 64-col S rows -> wave-local
// softmax). Frag layouts (m89/m97-verified): A/B lane=(m|n)=lane&15,
// k=quad*8+j from row-major-in-k LDS; C/D col=lane&15, row=quad*4+reg.
// ---------------------------------------------------------------------------
__global__ __launch_bounds__(256, 2) void fused_kernel(const float* __restrict__ neigh,
                                                       const u16* __restrict__ NH,
                                                       const u16* __restrict__ NL,
                                                       const int* __restrict__ nbr,
                                                       const u16* __restrict__ MT,
                                                       float* __restrict__ out,
                                                       float* __restrict__ Wsum) {
    __shared__ u16 Xh[64][72];   // X hi (also reused as M-chunk stage in Phase B)
    __shared__ u16 Xl[64][72];   // X lo
    __shared__ u16 Nh[64][72];   // node hi chunk [t][k]
    __shared__ u16 Nl[64][72];   // node lo chunk
    __shared__ u16 Ph[64][72];   // P bf16 [q][t]
    __shared__ float Wtmp[256];

    int b  = blockIdx.x >> 4;
    int i  = blockIdx.x & 15;
    int q0 = i << 6;

    int tid  = threadIdx.x;
    int w    = tid >> 6;         // wave 0..3
    int lane = tid & 63;
    int quad = lane >> 4;
    int c    = lane & 15;

    // neighbors_number: int64 per reference; harness may upload int32.
    // Values in [1,16] so nbr[1]==0 <=> int64 (high word of elem 0).
    int nb = (nbr[1] == 0) ? nbr[2 * b] : nbr[b];
    float rscale = rsqrtf((float)nb);

    const float* Xg  = neigh + ((size_t)b * Nc * Tc + q0) * Hc;
    const u16*   NHg = NH + (size_t)b * Tc * Hc;
    const u16*   NLg = NL + (size_t)b * Tc * Hc;
    const u16*   MTg = MT + (size_t)b * Hc * Tc;

    v4f acc[4];
#pragma unroll
    for (int nt = 0; nt < 4; nt++)
#pragma unroll
        for (int rg = 0; rg < 4; rg++) acc[nt][rg] = 0.f;

    // ---- Phase A: K=256 in chunks of 64 ----
    for (int k0 = 0; k0 < Hc; k0 += 64) {
        // stage X chunk (64q x 64k fp32 -> hi/lo bf16)
#pragma unroll
        for (int rep = 0; rep < 4; rep++) {
            int idx = rep * 256 + tid;
            int row = idx >> 4, c4 = idx & 15;
            float4 xv = *(const float4*)(Xg + (size_t)row * Hc + k0 + c4 * 4);
            ushort4 hs, ls;
            hs.x = f2bf(xv.x); ls.x = f2bf(xv.x - bf2f(hs.x));
            hs.y = f2bf(xv.y); ls.y = f2bf(xv.y - bf2f(hs.y));
            hs.z = f2bf(xv.z); ls.z = f2bf(xv.z - bf2f(hs.z));
            hs.w = f2bf(xv.w); ls.w = f2bf(xv.w - bf2f(hs.w));
            *(ushort4*)&Xh[row][c4 * 4] = hs;
            *(ushort4*)&Xl[row][c4 * 4] = ls;
        }
        // stage node chunk (precomputed bf16, plain copy)
#pragma unroll
        for (int rep = 0; rep < 2; rep++) {
            int idx = rep * 256 + tid;
            int row = idx >> 3, c8 = idx & 7;
            *(uint4*)&Nh[row][c8 * 8] = *(const uint4*)(NHg + (size_t)row * Hc + k0 + c8 * 8);
            *(uint4*)&Nl[row][c8 * 8] = *(const uint4*)(NLg + (size_t)row * Hc + k0 + c8 * 8);
        }
        __syncthreads();

#pragma unroll
        for (int ks = 0; ks < 64; ks += 32) {
            v8s ah = *(const v8s*)&Xh[w * 16 + c][ks + quad * 8];
            v8s al = *(const v8s*)&Xl[w * 16 + c][ks + quad * 8];
#pragma unroll
            for (int nt = 0; nt < 4; nt++) {
                v8s bh = *(const v8s*)&Nh[nt * 16 + c][ks + quad * 8];
                v8s bl = *(const v8s*)&Nl[nt * 16 + c][ks + quad * 8];
                acc[nt] = __builtin_amdgcn_mfma_f32_16x16x32_bf16(ah, bh, acc[nt], 0, 0, 0);
                acc[nt] = __builtin_amdgcn_mfma_f32_16x16x32_bf16(ah, bl, acc[nt], 0, 0, 0);
                acc[nt] = __builtin_amdgcn_mfma_f32_16x16x32_bf16(al, bh, acc[nt], 0, 0, 0);
            }
        }
        __syncthreads();
    }

    // ---- Softmax over t (C-layout: col = nt*16+c, row = w*16+quad*4+rg) ----
#pragma unroll
    for (int nt = 0; nt < 4; nt++)
#pragma unroll
        for (int rg = 0; rg < 4; rg++) acc[nt][rg] *= rscale;

#pragma unroll
    for (int rg = 0; rg < 4; rg++) {
        float m = fmaxf(fmaxf(acc[0][rg], acc[1][rg]), fmaxf(acc[2][rg], acc[3][rg]));
#pragma unroll
        for (int d = 1; d < 16; d <<= 1) m = fmaxf(m, __shfl_xor(m, d));
        float e0 = __expf(acc[0][rg] - m);
        float e1 = __expf(acc[1][rg] - m);
        float e2 = __expf(acc[2][rg] - m);
        float e3 = __expf(acc[3][rg] - m);
        float s = e0 + e1 + e2 + e3;
#pragma unroll
        for (int d = 1; d < 16; d <<= 1) s += __shfl_xor(s, d);
        float inv = 1.0f / s;
        acc[0][rg] = e0 * inv; acc[1][rg] = e1 * inv;
        acc[2][rg] = e2 * inv; acc[3][rg] = e3 * inv;
    }

    // Column sums for W: per lane partial over its 4 rows, reduce across quads.
#pragma unroll
    for (int nt = 0; nt < 4; nt++) {
        float cs = acc[nt][0] + acc[nt][1] + acc[nt][2] + acc[nt][3];
        cs += __shfl_xor(cs, 16);
        cs += __shfl_xor(cs, 32);
        if (quad == 0) Wtmp[w * 64 + nt * 16 + c] = cs;
    }

    // P -> LDS as bf16 (row = w*16+quad*4+rg, col = nt*16+c)
#pragma unroll
    for (int nt = 0; nt < 4; nt++)
#pragma unroll
        for (int rg = 0; rg < 4; rg++)
            Ph[w * 16 + quad * 4 + rg][nt * 16 + c] = f2bf(acc[nt][rg]);

    __syncthreads();

    if (tid < 64) {
        float s = Wtmp[tid] + Wtmp[64 + tid] + Wtmp[128 + tid] + Wtmp[192 + tid];
        atomicAdd(&Wsum[b * Tc + tid], s);
    }

    // ---- Phase B: out = P(64x64) @ M(64x256), bf16 MFMA, K=64 ----
    v8s pa0 = *(const v8s*)&Ph[w * 16 + c][quad * 8];
    v8s pa1 = *(const v8s*)&Ph[w * 16 + c][32 + quad * 8];

    for (int h0 = 0; h0 < Hc; h0 += 64) {
        // stage MT chunk (64h x 64t bf16) into Xh (Phase A done with it)
#pragma unroll
        for (int rep = 0; rep < 2; rep++) {
            int idx = rep * 256 + tid;
            int row = idx >> 3, c8 = idx & 7;
            *(uint4*)&Xh[row][c8 * 8] = *(const uint4*)(MTg + (size_t)(h0 + row) * Tc + c8 * 8);
        }
        __syncthreads();

        v4f oc[4];
#pragma unroll
        for (int ht = 0; ht < 4; ht++)
#pragma unroll
            for (int rg = 0; rg < 4; rg++) oc[ht][rg] = 0.f;

#pragma unroll
        for (int ht = 0; ht < 4; ht++) {
            v8s b0 = *(const v8s*)&Xh[ht * 16 + c][quad * 8];
            v8s b1 = *(const v8s*)&Xh[ht * 16 + c][32 + quad * 8];
            oc[ht] = __builtin_amdgcn_mfma_f32_16x16x32_bf16(pa0, b0, oc[ht], 0, 0, 0);
            oc[ht] = __builtin_amdgcn_mfma_f32_16x16x32_bf16(pa1, b1, oc[ht], 0, 0, 0);
        }

        float* ob = out + ((size_t)b * NTc + q0 + w * 16 + quad * 4) * Hc + h0 + c;
#pragma unroll
        for (int ht = 0; ht < 4; ht++)
#pragma unroll
            for (int rg = 0; rg < 4; rg++)
                ob[(size_t)rg * Hc + ht * 16] = oc[ht][rg];

        __syncthreads();   // before overwriting Xh next chunk
    }
}

// ---------------------------------------------------------------------------
// W[b,i,t] = Wsum[b,t] / 16  (independent of i)
// ---------------------------------------------------------------------------
__global__ __launch_bounds__(256) void wexp_kernel(const float* __restrict__ Wsum,
                                                   float* __restrict__ Wout) {
    int idx = blockIdx.x * 256 + threadIdx.x;   // over B*N*T = 32768
    int b = idx >> 10;
    int t = idx & 63;
    Wout[idx] = Wsum[b * Tc + t] * (1.0f / 16.0f);
}

// ---------------------------------------------------------------------------
extern "C" void kernel_launch(void* const* d_in, const int* in_sizes, int n_in,
                              void* d_out, int out_size, void* d_ws, size_t ws_size,
                              hipStream_t stream) {
    const float* node  = (const float*)d_in[0];   // (B,T,H)
    const float* neigh = (const float*)d_in[1];   // (B,N,T,H)
    const int*   nbr   = (const int*)d_in[2];     // (B,) int32/int64 (detected)

    float* out = (float*)d_out;                   // (B,NT,H) then W (B,N,T)

    u16* MTw = (u16*)d_ws;                        // [B][H][T] bf16 transposed mean
    u16* NHw = MTw + (size_t)Bc * Hc * Tc;        // [B][T][H] bf16 node hi
    u16* NLw = NHw + (size_t)Bc * Tc * Hc;        // [B][T][H] bf16 node lo
    float* Ww = (float*)(NLw + (size_t)Bc * Tc * Hc);  // [B][T] fp32

    prep_kernel <<<160, 256, 0, stream>>>(neigh, node, MTw, NHw, NLw, Ww);
    fused_kernel<<<512, 256, 0, stream>>>(neigh, NHw, NLw, nbr, MTw, out, Ww);
    wexp_kernel <<<128, 256, 0, stream>>>(Ww, out + (size_t)Bc * NTc * Hc);
}